// Round 1
// baseline (1155.512 us; speedup 1.0000x reference)
//
#include <hip/hip_runtime.h>

#define EPSN 1e-12f

// ---------------- pre: h0 = relu(x @ pre_w + pre_b), x:[N,5] w:[5,32] ----------
__global__ void pre_linear(const float* __restrict__ x, const float* __restrict__ w,
                           const float* __restrict__ b, float* __restrict__ h0, int n) {
    int idx = blockIdx.x * blockDim.x + threadIdx.x;
    if (idx >= n * 32) return;
    int node = idx >> 5, j = idx & 31;
    float v = b[j];
#pragma unroll
    for (int k = 0; k < 5; ++k) v += x[node * 5 + k] * w[k * 32 + j];
    h0[idx] = fmaxf(v, 0.f);
}

// ---------------- degree: cnt[dst] += 1 ---------------------------------------
__global__ void degree_k(const int* __restrict__ dst, float* __restrict__ cnt, int e) {
    int i = blockIdx.x * blockDim.x + threadIdx.x;
    if (i < e) atomicAdd(&cnt[dst[i]], 1.0f);
}

// ---------------- scatter: agg[dst] += h[src], D features per edge ------------
template <int D>
__global__ void scatter_k(const int* __restrict__ src, const int* __restrict__ dst,
                          const float* __restrict__ h, float* __restrict__ agg, int e) {
    int idx = blockIdx.x * blockDim.x + threadIdx.x;
    if (idx >= e * D) return;
    int eid = idx / D;
    int f = idx & (D - 1);
    atomicAdd(&agg[dst[eid] * D + f], h[src[eid] * D + f]);
}

// ---------------- combine: out = norm(agg/cnt @ wl + bl + h @ wr), relu -------
// one 64-lane wave per node; lane j owns output feature j (output dim = 64)
template <int K>
__global__ __launch_bounds__(256) void combine_k(
    const float* __restrict__ agg, const float* __restrict__ hin,
    const float* __restrict__ cnt, const float* __restrict__ wl,
    const float* __restrict__ bl, const float* __restrict__ wr,
    float* __restrict__ hout, int n) {
    __shared__ float s_wl[K * 64];
    __shared__ float s_wr[K * 64];
    __shared__ float s_bl[64];
    for (int i = threadIdx.x; i < K * 64; i += blockDim.x) {
        s_wl[i] = wl[i];
        s_wr[i] = wr[i];
    }
    if (threadIdx.x < 64) s_bl[threadIdx.x] = bl[threadIdx.x];
    __syncthreads();
    int gtid = blockIdx.x * blockDim.x + threadIdx.x;
    int node = gtid >> 6;
    int j = gtid & 63;
    if (node >= n) return;
    float c = cnt[node];
    float inv = (c > 0.f) ? (1.0f / c) : 0.0f;   // mean-agg; cnt==0 -> 0
    float v = s_bl[j];
#pragma unroll 8
    for (int k = 0; k < K; ++k) {
        float a = agg[node * K + k] * inv;       // broadcast within wave
        float hk = hin[node * K + k];
        v += a * s_wl[k * 64 + j] + hk * s_wr[k * 64 + j];
    }
    // L2 norm across the 64 lanes (one node per wave)
    float sq = v * v;
#pragma unroll
    for (int o = 32; o > 0; o >>= 1) sq += __shfl_xor(sq, o);
    float nrm = sqrtf(sq);
    v = v / fmaxf(nrm, EPSN);
    hout[node * 64 + j] = fmaxf(v, 0.f);         // relu after normalize
}

// ---------------- pool: s[batch[n]] += h2[n]; c[batch[n]] += 1 ----------------
__global__ void pool_k(const float* __restrict__ h, const int* __restrict__ batch,
                       float* __restrict__ s, float* __restrict__ c, int n) {
    int idx = blockIdx.x * blockDim.x + threadIdx.x;
    if (idx >= n * 64) return;
    int node = idx >> 6, f = idx & 63;
    int g = batch[node];
    atomicAdd(&s[g * 64 + f], h[idx]);
    if (f == 0) atomicAdd(&c[g], 1.0f);
}

// ---------------- head MLP: 64 -> 64 -> 16 -> 1 per graph ---------------------
__global__ void mlp_k(const float* __restrict__ s, const float* __restrict__ c,
                      const float* __restrict__ p1w, const float* __restrict__ p1b,
                      const float* __restrict__ p2w, const float* __restrict__ p2b,
                      const float* __restrict__ ow, const float* __restrict__ ob,
                      float* __restrict__ out) {
    __shared__ float g[64], a1[64], a2[16];
    int gi = blockIdx.x, j = threadIdx.x;
    float cg = c[gi];
    g[j] = s[gi * 64 + j] / fmaxf(cg, 1.0f);
    __syncthreads();
    float v = p1b[j];
#pragma unroll 8
    for (int k = 0; k < 64; ++k) v += g[k] * p1w[k * 64 + j];
    a1[j] = fmaxf(v, 0.f);
    __syncthreads();
    if (j < 16) {
        float v2 = p2b[j];
#pragma unroll 8
        for (int k = 0; k < 64; ++k) v2 += a1[k] * p2w[k * 16 + j];
        a2[j] = fmaxf(v2, 0.f);
    }
    __syncthreads();
    if (j == 0) {
        float v3 = ob[0];
#pragma unroll
        for (int k = 0; k < 16; ++k) v3 += a2[k] * ow[k];
        out[gi] = v3;
    }
}

extern "C" void kernel_launch(void* const* d_in, const int* in_sizes, int n_in,
                              void* d_out, int out_size, void* d_ws, size_t ws_size,
                              hipStream_t stream) {
    const float* x     = (const float*)d_in[0];
    const int*   ei    = (const int*)d_in[1];
    const int*   batch = (const int*)d_in[2];
    // d_in[3] = num_graphs scalar (== out_size), unused on host
    const float* pre_w = (const float*)d_in[4];
    const float* pre_b = (const float*)d_in[5];
    const float* c1_wl = (const float*)d_in[6];
    const float* c1_bl = (const float*)d_in[7];
    const float* c1_wr = (const float*)d_in[8];
    const float* c2_wl = (const float*)d_in[9];
    const float* c2_bl = (const float*)d_in[10];
    const float* c2_wr = (const float*)d_in[11];
    const float* p1w   = (const float*)d_in[12];
    const float* p1b   = (const float*)d_in[13];
    const float* p2w   = (const float*)d_in[14];
    const float* p2b   = (const float*)d_in[15];
    const float* ow    = (const float*)d_in[16];
    const float* ob    = (const float*)d_in[17];

    const int N = in_sizes[0] / 5;
    const int E = in_sizes[1] / 2;
    const int G = out_size;
    const int* src = ei;
    const int* dst = ei + E;

    float* ws  = (float*)d_ws;
    float* h0  = ws;                    // N*32
    float* h1  = h0 + (size_t)N * 32;   // N*64
    float* agg = h1 + (size_t)N * 64;   // N*64 (reused; conv2 output written in place)
    float* cnt = agg + (size_t)N * 64;  // N
    float* sg  = cnt + N;               // G*64
    float* cg  = sg + (size_t)G * 64;   // G  (contiguous with sg)
    float* h2  = agg;

    hipMemsetAsync(cnt, 0, (size_t)N * sizeof(float), stream);
    hipMemsetAsync(sg, 0, (size_t)(G * 64 + G) * sizeof(float), stream);
    hipMemsetAsync(agg, 0, (size_t)N * 32 * sizeof(float), stream);

    pre_linear<<<(N * 32 + 255) / 256, 256, 0, stream>>>(x, pre_w, pre_b, h0, N);
    degree_k<<<(E + 255) / 256, 256, 0, stream>>>(dst, cnt, E);

    // conv1: 32-wide
    scatter_k<32><<<(E * 32 + 255) / 256, 256, 0, stream>>>(src, dst, h0, agg, E);
    combine_k<32><<<(N * 64 + 255) / 256, 256, 0, stream>>>(agg, h0, cnt, c1_wl, c1_bl,
                                                            c1_wr, h1, N);
    // conv2: 64-wide (re-zero agg first)
    hipMemsetAsync(agg, 0, (size_t)N * 64 * sizeof(float), stream);
    scatter_k<64><<<(E * 64 + 255) / 256, 256, 0, stream>>>(src, dst, h1, agg, E);
    combine_k<64><<<(N * 64 + 255) / 256, 256, 0, stream>>>(agg, h1, cnt, c2_wl, c2_bl,
                                                            c2_wr, h2, N);

    pool_k<<<(N * 64 + 255) / 256, 256, 0, stream>>>(h2, batch, sg, cg, N);
    mlp_k<<<G, 64, 0, stream>>>(sg, cg, p1w, p1b, p2w, p2b, ow, ob, (float*)d_out);
}

// Round 2
// 888.743 us; speedup vs baseline: 1.3002x; 1.3002x over previous
//
#include <hip/hip_runtime.h>

#define EPSN 1e-12f

// ---------------- pre: h0 = relu(x @ pre_w + pre_b), x:[N,5] w:[5,32] ----------
__global__ void pre_linear(const float* __restrict__ x, const float* __restrict__ w,
                           const float* __restrict__ b, float* __restrict__ h0, int n) {
    int idx = blockIdx.x * blockDim.x + threadIdx.x;
    if (idx >= n * 32) return;
    int node = idx >> 5, j = idx & 31;
    float v = b[j];
#pragma unroll
    for (int k = 0; k < 5; ++k) v += x[node * 5 + k] * w[k * 32 + j];
    h0[idx] = fmaxf(v, 0.f);
}

// ---------------- CSR build: histogram -> scan -> fill ------------------------
__global__ void hist_k(const int* __restrict__ dst, int* __restrict__ deg, int e) {
    int i = blockIdx.x * blockDim.x + threadIdx.x;
    if (i < e) atomicAdd(&deg[dst[i]], 1);
}

// per-block exclusive scan; block totals to partials
__global__ void scan_block_k(const int* __restrict__ deg, int* __restrict__ rofs,
                             int* __restrict__ partials, int n) {
    __shared__ int wsum[8];
    int i = blockIdx.x * 256 + threadIdx.x;
    int x = (i < n) ? deg[i] : 0;
    int lane = threadIdx.x & 63, w = threadIdx.x >> 6;
    int inc = x;
#pragma unroll
    for (int o = 1; o < 64; o <<= 1) {
        int t = __shfl_up(inc, o);
        if (lane >= o) inc += t;
    }
    if (lane == 63) wsum[w] = inc;
    __syncthreads();
    if (threadIdx.x == 0) {
        int s = 0;
#pragma unroll
        for (int k = 0; k < 4; ++k) { int t = wsum[k]; wsum[k] = s; s += t; }
        wsum[4] = s;
    }
    __syncthreads();
    if (i < n) rofs[i] = inc - x + wsum[w];
    if (threadIdx.x == 255) partials[blockIdx.x] = wsum[4];
}

// single-block exclusive scan of block partials (nb ~ 391)
__global__ void scan_partials_k(int* __restrict__ partials, int nb) {
    int lane = threadIdx.x;  // 64 threads
    int run = 0;
    for (int base = 0; base < nb; base += 64) {
        int i = base + lane;
        int x = (i < nb) ? partials[i] : 0;
        int inc = x;
#pragma unroll
        for (int o = 1; o < 64; o <<= 1) {
            int t = __shfl_up(inc, o);
            if (lane >= o) inc += t;
        }
        if (i < nb) partials[i] = inc - x + run;
        run += __shfl(inc, 63);
    }
}

__global__ void add_offs_k(int* __restrict__ rofs, int* __restrict__ wptr,
                           const int* __restrict__ partials, int n, int e) {
    int i = blockIdx.x * 256 + threadIdx.x;
    if (i < n) {
        int v = rofs[i] + partials[i >> 8];
        rofs[i] = v;
        wptr[i] = v;
    }
    if (i == n) rofs[n] = e;
}

__global__ void fill_k(const int* __restrict__ src, const int* __restrict__ dst,
                       int* __restrict__ wptr, int* __restrict__ csr, int e) {
    int i = blockIdx.x * blockDim.x + threadIdx.x;
    if (i < e) {
        int p = atomicAdd(&wptr[dst[i]], 1);
        csr[p] = src[i];
    }
}

// ---------------- fused gather-mean + SAGE combine + L2norm + relu ------------
// one 64-lane wave per node; lane j owns output feature j (out dim 64)
template <int K>
__global__ __launch_bounds__(256) void conv_fused(
    const int* __restrict__ rofs, const int* __restrict__ csr,
    const float* __restrict__ hin, const float* __restrict__ wl,
    const float* __restrict__ bl, const float* __restrict__ wr,
    float* __restrict__ hout, int n) {
    __shared__ float s_wl[K * 64];
    __shared__ float s_wr[K * 64];
    __shared__ float s_bl[64];
    for (int i = threadIdx.x; i < K * 64; i += 256) {
        s_wl[i] = wl[i];
        s_wr[i] = wr[i];
    }
    if (threadIdx.x < 64) s_bl[threadIdx.x] = bl[threadIdx.x];
    __syncthreads();
    int node = blockIdx.x * 4 + (threadIdx.x >> 6);
    int j = threadIdx.x & 63;
    if (node >= n) return;
    int beg = rofs[node], end = rofs[node + 1];
    int f = j & (K - 1);
    float a0 = 0.f, a1 = 0.f, a2 = 0.f, a3 = 0.f;
    int e = beg;
    for (; e + 4 <= end; e += 4) {
        int s0 = csr[e], s1 = csr[e + 1], s2 = csr[e + 2], s3 = csr[e + 3];
        a0 += hin[(size_t)s0 * K + f];
        a1 += hin[(size_t)s1 * K + f];
        a2 += hin[(size_t)s2 * K + f];
        a3 += hin[(size_t)s3 * K + f];
    }
    for (; e < end; ++e) a0 += hin[(size_t)csr[e] * K + f];
    float a = (a0 + a1) + (a2 + a3);
    int d = end - beg;
    float inv = (d > 0) ? 1.0f / (float)d : 0.0f;  // mean-agg; deg==0 -> 0
    a *= inv;
    float hown = hin[(size_t)node * K + f];
    float v = s_bl[j];
#pragma unroll
    for (int k = 0; k < K; ++k) {
        float ak = __shfl(a, k);
        float hk = __shfl(hown, k);
        v = fmaf(ak, s_wl[k * 64 + j], v);
        v = fmaf(hk, s_wr[k * 64 + j], v);
    }
    float sq = v * v;
#pragma unroll
    for (int o = 32; o > 0; o >>= 1) sq += __shfl_xor(sq, o);
    v = v / fmaxf(sqrtf(sq), EPSN);
    hout[(size_t)node * 64 + j] = fmaxf(v, 0.f);
}

// ---------------- pool: s[batch[n]] += h2[n]; c[batch[n]] += 1 ----------------
__global__ void pool_k(const float* __restrict__ h, const int* __restrict__ batch,
                       float* __restrict__ s, float* __restrict__ c, int n) {
    int idx = blockIdx.x * blockDim.x + threadIdx.x;
    if (idx >= n * 64) return;
    int node = idx >> 6, f = idx & 63;
    int g = batch[node];
    atomicAdd(&s[g * 64 + f], h[idx]);
    if (f == 0) atomicAdd(&c[g], 1.0f);
}

// ---------------- head MLP: 64 -> 64 -> 16 -> 1 per graph ---------------------
__global__ void mlp_k(const float* __restrict__ s, const float* __restrict__ c,
                      const float* __restrict__ p1w, const float* __restrict__ p1b,
                      const float* __restrict__ p2w, const float* __restrict__ p2b,
                      const float* __restrict__ ow, const float* __restrict__ ob,
                      float* __restrict__ out) {
    __shared__ float g[64], a1[64], a2[16];
    int gi = blockIdx.x, j = threadIdx.x;
    float cg = c[gi];
    g[j] = s[gi * 64 + j] / fmaxf(cg, 1.0f);
    __syncthreads();
    float v = p1b[j];
#pragma unroll 8
    for (int k = 0; k < 64; ++k) v += g[k] * p1w[k * 64 + j];
    a1[j] = fmaxf(v, 0.f);
    __syncthreads();
    if (j < 16) {
        float v2 = p2b[j];
#pragma unroll 8
        for (int k = 0; k < 64; ++k) v2 += a1[k] * p2w[k * 16 + j];
        a2[j] = fmaxf(v2, 0.f);
    }
    __syncthreads();
    if (j == 0) {
        float v3 = ob[0];
#pragma unroll
        for (int k = 0; k < 16; ++k) v3 += a2[k] * ow[k];
        out[gi] = v3;
    }
}

extern "C" void kernel_launch(void* const* d_in, const int* in_sizes, int n_in,
                              void* d_out, int out_size, void* d_ws, size_t ws_size,
                              hipStream_t stream) {
    const float* x     = (const float*)d_in[0];
    const int*   ei    = (const int*)d_in[1];
    const int*   batch = (const int*)d_in[2];
    const float* pre_w = (const float*)d_in[4];
    const float* pre_b = (const float*)d_in[5];
    const float* c1_wl = (const float*)d_in[6];
    const float* c1_bl = (const float*)d_in[7];
    const float* c1_wr = (const float*)d_in[8];
    const float* c2_wl = (const float*)d_in[9];
    const float* c2_bl = (const float*)d_in[10];
    const float* c2_wr = (const float*)d_in[11];
    const float* p1w   = (const float*)d_in[12];
    const float* p1b   = (const float*)d_in[13];
    const float* p2w   = (const float*)d_in[14];
    const float* p2b   = (const float*)d_in[15];
    const float* ow    = (const float*)d_in[16];
    const float* ob    = (const float*)d_in[17];

    const int N = in_sizes[0] / 5;
    const int E = in_sizes[1] / 2;
    const int G = out_size;
    const int NB = (N + 255) / 256;
    const int* src = ei;
    const int* dst = ei + E;

    // workspace layout
    float* bufA = (float*)d_ws;            // N*64 floats: h0 (first N*32), later h2
    float* h1   = bufA + (size_t)N * 64;   // N*64
    int* deg      = (int*)(h1 + (size_t)N * 64);  // N
    int* rofs     = deg + N;               // N+1
    int* wptr     = rofs + N + 1;          // N
    int* partials = wptr + N;              // NB
    int* csr      = partials + NB;         // E
    float* sg     = (float*)(csr + E);     // G*64
    float* cg     = sg + (size_t)G * 64;   // G
    float* h0 = bufA;
    float* h2 = bufA;

    hipMemsetAsync(deg, 0, (size_t)N * sizeof(int), stream);
    hipMemsetAsync(sg, 0, (size_t)(G * 64 + G) * sizeof(float), stream);

    pre_linear<<<(N * 32 + 255) / 256, 256, 0, stream>>>(x, pre_w, pre_b, h0, N);

    // CSR build (shared by both convs)
    hist_k<<<(E + 255) / 256, 256, 0, stream>>>(dst, deg, E);
    scan_block_k<<<NB, 256, 0, stream>>>(deg, rofs, partials, N);
    scan_partials_k<<<1, 64, 0, stream>>>(partials, NB);
    add_offs_k<<<(N + 256) / 256, 256, 0, stream>>>(rofs, wptr, partials, N, E);
    fill_k<<<(E + 255) / 256, 256, 0, stream>>>(src, dst, wptr, csr, E);

    conv_fused<32><<<(N + 3) / 4, 256, 0, stream>>>(rofs, csr, h0, c1_wl, c1_bl, c1_wr,
                                                    h1, N);
    conv_fused<64><<<(N + 3) / 4, 256, 0, stream>>>(rofs, csr, h1, c2_wl, c2_bl, c2_wr,
                                                    h2, N);

    pool_k<<<(N * 64 + 255) / 256, 256, 0, stream>>>(h2, batch, sg, cg, N);
    mlp_k<<<G, 64, 0, stream>>>(sg, cg, p1w, p1b, p2w, p2b, ow, ob, (float*)d_out);
}

// Round 3
// 671.032 us; speedup vs baseline: 1.7220x; 1.3244x over previous
//
#include <hip/hip_runtime.h>

#define EPSN 1e-12f

// ---------------- pre: h0 = relu(x @ pre_w + pre_b), x:[N,5] w:[5,32] ----------
__global__ void pre_linear(const float* __restrict__ x, const float* __restrict__ w,
                           const float* __restrict__ b, float* __restrict__ h0, int n) {
    int idx = blockIdx.x * blockDim.x + threadIdx.x;
    if (idx >= n * 32) return;
    int node = idx >> 5, j = idx & 31;
    float v = b[j];
#pragma unroll
    for (int k = 0; k < 5; ++k) v += x[node * 5 + k] * w[k * 32 + j];
    h0[idx] = fmaxf(v, 0.f);
}

// ---------------- CSR build: histogram -> scan -> fill ------------------------
__global__ void hist_k(const int* __restrict__ dst, int* __restrict__ deg, int e) {
    int i = blockIdx.x * blockDim.x + threadIdx.x;
    if (i < e) atomicAdd(&deg[dst[i]], 1);
}

__global__ void scan_block_k(const int* __restrict__ deg, int* __restrict__ rofs,
                             int* __restrict__ partials, int n) {
    __shared__ int wsum[8];
    int i = blockIdx.x * 256 + threadIdx.x;
    int x = (i < n) ? deg[i] : 0;
    int lane = threadIdx.x & 63, w = threadIdx.x >> 6;
    int inc = x;
#pragma unroll
    for (int o = 1; o < 64; o <<= 1) {
        int t = __shfl_up(inc, o);
        if (lane >= o) inc += t;
    }
    if (lane == 63) wsum[w] = inc;
    __syncthreads();
    if (threadIdx.x == 0) {
        int s = 0;
#pragma unroll
        for (int k = 0; k < 4; ++k) { int t = wsum[k]; wsum[k] = s; s += t; }
        wsum[4] = s;
    }
    __syncthreads();
    if (i < n) rofs[i] = inc - x + wsum[w];
    if (threadIdx.x == 255) partials[blockIdx.x] = wsum[4];
}

__global__ void scan_partials_k(int* __restrict__ partials, int nb) {
    int lane = threadIdx.x;  // 64 threads
    int run = 0;
    for (int base = 0; base < nb; base += 64) {
        int i = base + lane;
        int x = (i < nb) ? partials[i] : 0;
        int inc = x;
#pragma unroll
        for (int o = 1; o < 64; o <<= 1) {
            int t = __shfl_up(inc, o);
            if (lane >= o) inc += t;
        }
        if (i < nb) partials[i] = inc - x + run;
        run += __shfl(inc, 63);
    }
}

__global__ void add_offs_k(int* __restrict__ rofs, int* __restrict__ wptr,
                           const int* __restrict__ partials, int n, int e) {
    int i = blockIdx.x * 256 + threadIdx.x;
    if (i < n) {
        int v = rofs[i] + partials[i >> 8];
        rofs[i] = v;
        wptr[i] = v;
    }
    if (i == n) rofs[n] = e;
}

__global__ void fill_k(const int* __restrict__ src, const int* __restrict__ dst,
                       int* __restrict__ wptr, int* __restrict__ csr, int e) {
    int i = blockIdx.x * blockDim.x + threadIdx.x;
    if (i < e) {
        int p = atomicAdd(&wptr[dst[i]], 1);
        csr[p] = src[i];
    }
}

// ---------------- fused gather-mean + SAGE combine + L2norm + relu ------------
// one 64-lane wave per node; lane j owns output feature j (out dim 64).
// block = 1024 threads (16 nodes) so the LDS weight stage is amortized 4x and
// 2 blocks/CU -> 32 waves/CU (occupancy was the round-2 limiter at 39%).
template <int K>
__global__ __launch_bounds__(1024, 8) void conv_fused(
    const int* __restrict__ rofs, const int* __restrict__ csr,
    const float* __restrict__ hin, const float* __restrict__ wl,
    const float* __restrict__ bl, const float* __restrict__ wr,
    float* __restrict__ hout, int n) {
    __shared__ float s_wl[K * 64];
    __shared__ float s_wr[K * 64];
    __shared__ float s_bl[64];
    for (int i = threadIdx.x; i < K * 64; i += 1024) {
        s_wl[i] = wl[i];
        s_wr[i] = wr[i];
    }
    if (threadIdx.x < 64) s_bl[threadIdx.x] = bl[threadIdx.x];
    __syncthreads();
    int node = blockIdx.x * 16 + (threadIdx.x >> 6);
    int j = threadIdx.x & 63;
    if (node >= n) return;
    int beg = rofs[node], end = rofs[node + 1];
    int f = j & (K - 1);
    float a0 = 0.f, a1 = 0.f, a2 = 0.f, a3 = 0.f;
    int e = beg;
    for (; e + 4 <= end; e += 4) {
        int s0 = csr[e], s1 = csr[e + 1], s2 = csr[e + 2], s3 = csr[e + 3];
        a0 += hin[(size_t)s0 * K + f];
        a1 += hin[(size_t)s1 * K + f];
        a2 += hin[(size_t)s2 * K + f];
        a3 += hin[(size_t)s3 * K + f];
    }
    for (; e < end; ++e) a0 += hin[(size_t)csr[e] * K + f];
    float a = (a0 + a1) + (a2 + a3);
    int d = end - beg;
    float inv = (d > 0) ? 1.0f / (float)d : 0.0f;  // mean-agg; deg==0 -> 0
    a *= inv;
    float hown = hin[(size_t)node * K + f];
    float v = s_bl[j];
#pragma unroll
    for (int k = 0; k < K; ++k) {
        float ak = __shfl(a, k);
        float hk = __shfl(hown, k);
        v = fmaf(ak, s_wl[k * 64 + j], v);
        v = fmaf(hk, s_wr[k * 64 + j], v);
    }
    float sq = v * v;
#pragma unroll
    for (int o = 32; o > 0; o >>= 1) sq += __shfl_xor(sq, o);
    v = v / fmaxf(sqrtf(sq), EPSN);
    hout[(size_t)node * 64 + j] = fmaxf(v, 0.f);
}

// ---------------- fused pool (batch is sorted) + head MLP ---------------------
// one block (256 thr) per graph: binary-search node range, 4-wave coalesced
// mean-reduce, wave 0 runs 64->64->16->1 MLP. No atomics, no sg/cg memsets.
__global__ __launch_bounds__(256) void pool_mlp_k(
    const float* __restrict__ h, const int* __restrict__ batch, int n,
    const float* __restrict__ p1w, const float* __restrict__ p1b,
    const float* __restrict__ p2w, const float* __restrict__ p2b,
    const float* __restrict__ ow, const float* __restrict__ ob,
    float* __restrict__ out) {
    __shared__ float part[4][64];
    __shared__ float gmean[64];
    __shared__ float a1[64];
    __shared__ float a2[16];
    int g = blockIdx.x;
    int w = threadIdx.x >> 6, j = threadIdx.x & 63;
    int lo = 0, hi = n;
    while (lo < hi) { int m = (lo + hi) >> 1; if (batch[m] < g) lo = m + 1; else hi = m; }
    int start = lo;
    hi = n;
    while (lo < hi) { int m = (lo + hi) >> 1; if (batch[m] < g + 1) lo = m + 1; else hi = m; }
    int end = lo;
    float acc = 0.f;
    for (int node = start + w; node < end; node += 4)
        acc += h[(size_t)node * 64 + j];
    part[w][j] = acc;
    __syncthreads();
    if (w == 0) {
        float s = part[0][j] + part[1][j] + part[2][j] + part[3][j];
        float c = (float)(end - start);
        gmean[j] = s / fmaxf(c, 1.0f);
    }
    __syncthreads();
    if (w == 0) {
        float v = p1b[j];
#pragma unroll 8
        for (int k = 0; k < 64; ++k) v = fmaf(gmean[k], p1w[k * 64 + j], v);
        a1[j] = fmaxf(v, 0.f);
    }
    __syncthreads();
    if (w == 0 && j < 16) {
        float v2 = p2b[j];
#pragma unroll 8
        for (int k = 0; k < 64; ++k) v2 = fmaf(a1[k], p2w[k * 16 + j], v2);
        a2[j] = fmaxf(v2, 0.f);
    }
    __syncthreads();
    if (threadIdx.x == 0) {
        float v3 = ob[0];
#pragma unroll
        for (int k = 0; k < 16; ++k) v3 = fmaf(a2[k], ow[k], v3);
        out[g] = v3;
    }
}

extern "C" void kernel_launch(void* const* d_in, const int* in_sizes, int n_in,
                              void* d_out, int out_size, void* d_ws, size_t ws_size,
                              hipStream_t stream) {
    const float* x     = (const float*)d_in[0];
    const int*   ei    = (const int*)d_in[1];
    const int*   batch = (const int*)d_in[2];
    const float* pre_w = (const float*)d_in[4];
    const float* pre_b = (const float*)d_in[5];
    const float* c1_wl = (const float*)d_in[6];
    const float* c1_bl = (const float*)d_in[7];
    const float* c1_wr = (const float*)d_in[8];
    const float* c2_wl = (const float*)d_in[9];
    const float* c2_bl = (const float*)d_in[10];
    const float* c2_wr = (const float*)d_in[11];
    const float* p1w   = (const float*)d_in[12];
    const float* p1b   = (const float*)d_in[13];
    const float* p2w   = (const float*)d_in[14];
    const float* p2b   = (const float*)d_in[15];
    const float* ow    = (const float*)d_in[16];
    const float* ob    = (const float*)d_in[17];

    const int N = in_sizes[0] / 5;
    const int E = in_sizes[1] / 2;
    const int G = out_size;
    const int NB = (N + 255) / 256;
    const int* src = ei;
    const int* dst = ei + E;

    // workspace layout
    float* bufA = (float*)d_ws;            // N*64 floats: h0 (first N*32), later h2
    float* h1   = bufA + (size_t)N * 64;   // N*64
    int* deg      = (int*)(h1 + (size_t)N * 64);  // N
    int* rofs     = deg + N;               // N+1
    int* wptr     = rofs + N + 1;          // N
    int* partials = wptr + N;              // NB
    int* csr      = partials + NB;         // E
    float* h0 = bufA;
    float* h2 = bufA;

    hipMemsetAsync(deg, 0, (size_t)N * sizeof(int), stream);

    pre_linear<<<(N * 32 + 255) / 256, 256, 0, stream>>>(x, pre_w, pre_b, h0, N);

    // CSR build (shared by both convs)
    hist_k<<<(E + 255) / 256, 256, 0, stream>>>(dst, deg, E);
    scan_block_k<<<NB, 256, 0, stream>>>(deg, rofs, partials, N);
    scan_partials_k<<<1, 64, 0, stream>>>(partials, NB);
    add_offs_k<<<(N + 256) / 256, 256, 0, stream>>>(rofs, wptr, partials, N, E);
    fill_k<<<(E + 255) / 256, 256, 0, stream>>>(src, dst, wptr, csr, E);

    conv_fused<32><<<(N + 15) / 16, 1024, 0, stream>>>(rofs, csr, h0, c1_wl, c1_bl,
                                                       c1_wr, h1, N);
    conv_fused<64><<<(N + 15) / 16, 1024, 0, stream>>>(rofs, csr, h1, c2_wl, c2_bl,
                                                       c2_wr, h2, N);

    pool_mlp_k<<<G, 256, 0, stream>>>(h2, batch, N, p1w, p1b, p2w, p2b, ow, ob,
                                      (float*)d_out);
}

// Round 4
// 513.566 us; speedup vs baseline: 2.2500x; 1.3066x over previous
//
#include <hip/hip_runtime.h>

#define EPSN 1e-12f

using frag_ab = __attribute__((ext_vector_type(8))) short;   // 8 bf16
using frag_cd = __attribute__((ext_vector_type(4))) float;   // 4 fp32

__device__ inline unsigned short f2bf(float x) {
    union { float f; unsigned u; } v; v.f = x;
    unsigned r = v.u + 0x7fffu + ((v.u >> 16) & 1u);   // round-to-nearest-even
    return (unsigned short)(r >> 16);
}
__device__ inline float bf2f(unsigned short b) {
    union { unsigned u; float f; } v; v.u = ((unsigned)b) << 16; return v.f;
}

// ---------------- pre: h0 = relu(x @ pre_w + pre_b) -> bf16 [N,32] ------------
__global__ void pre_linear(const float* __restrict__ x, const float* __restrict__ w,
                           const float* __restrict__ b, unsigned short* __restrict__ h0,
                           int n) {
    int idx = blockIdx.x * blockDim.x + threadIdx.x;
    if (idx >= n * 32) return;
    int node = idx >> 5, j = idx & 31;
    float v = b[j];
#pragma unroll
    for (int k = 0; k < 5; ++k) v += x[node * 5 + k] * w[k * 32 + j];
    h0[idx] = f2bf(fmaxf(v, 0.f));
}

// ---------------- CSR build: histogram -> scan -> fill ------------------------
__global__ void hist_k(const int* __restrict__ dst, int* __restrict__ deg, int e) {
    int i = blockIdx.x * blockDim.x + threadIdx.x;
    if (i < e) atomicAdd(&deg[dst[i]], 1);
}

__global__ void scan_block_k(const int* __restrict__ deg, int* __restrict__ rofs,
                             int* __restrict__ partials, int n) {
    __shared__ int wsum[8];
    int i = blockIdx.x * 256 + threadIdx.x;
    int x = (i < n) ? deg[i] : 0;
    int lane = threadIdx.x & 63, w = threadIdx.x >> 6;
    int inc = x;
#pragma unroll
    for (int o = 1; o < 64; o <<= 1) {
        int t = __shfl_up(inc, o);
        if (lane >= o) inc += t;
    }
    if (lane == 63) wsum[w] = inc;
    __syncthreads();
    if (threadIdx.x == 0) {
        int s = 0;
#pragma unroll
        for (int k = 0; k < 4; ++k) { int t = wsum[k]; wsum[k] = s; s += t; }
        wsum[4] = s;
    }
    __syncthreads();
    if (i < n) rofs[i] = inc - x + wsum[w];
    if (threadIdx.x == 255) partials[blockIdx.x] = wsum[4];
}

__global__ void scan_partials_k(int* __restrict__ partials, int nb) {
    int lane = threadIdx.x;  // 64 threads
    int run = 0;
    for (int base = 0; base < nb; base += 64) {
        int i = base + lane;
        int x = (i < nb) ? partials[i] : 0;
        int inc = x;
#pragma unroll
        for (int o = 1; o < 64; o <<= 1) {
            int t = __shfl_up(inc, o);
            if (lane >= o) inc += t;
        }
        if (i < nb) partials[i] = inc - x + run;
        run += __shfl(inc, 63);
    }
}

__global__ void add_offs_k(int* __restrict__ rofs, int* __restrict__ wptr,
                           const int* __restrict__ partials, int n, int e) {
    int i = blockIdx.x * 256 + threadIdx.x;
    if (i < n) {
        int v = rofs[i] + partials[i >> 8];
        rofs[i] = v;
        wptr[i] = v;
    }
    if (i == n) rofs[n] = e;
}

__global__ void fill_k(const int* __restrict__ src, const int* __restrict__ dst,
                       int* __restrict__ wptr, int* __restrict__ csr, int e) {
    int i = blockIdx.x * blockDim.x + threadIdx.x;
    if (i < e) {
        int p = atomicAdd(&wptr[dst[i]], 1);
        csr[p] = src[i];
    }
}

// ---------------- SAGE conv via MFMA ------------------------------------------
// Block = 256 thr (4 waves) = 64 nodes. Wave w gathers nodes w*16..w*16+15
// (lane=feature, bf16 rows, 2-4 edges per wave-instr), writes [agg|self] bf16
// rows to LDS. Then wave w computes j-tile w for all 4 M-tiles with
// mfma_f32_16x16x32_bf16; weights live in VGPR B-fragments (built once).
// Epilogue: bias, cross-wave L2 norm via LDS, relu, store.
template <int KIN, bool OUTBF16>
__global__ __launch_bounds__(256) void conv_mfma(
    const int* __restrict__ rofs, const int* __restrict__ csr,
    const unsigned short* __restrict__ hin, const float* __restrict__ wl,
    const float* __restrict__ bl, const float* __restrict__ wr,
    void* __restrict__ hout, int n) {
    constexpr int KT = 2 * KIN;    // concat [agg|self]
    constexpr int ST = KT + 8;     // LDS row stride in ushorts (pad, keeps 16B align)
    constexpr int KS = KT / 32;    // MFMA k-steps
    __shared__ unsigned short __attribute__((aligned(16))) Ab[64 * ST];
    __shared__ float __attribute__((aligned(16))) Nb[4 * 64];

    int w = threadIdx.x >> 6;      // wave id == j-tile
    int lane = threadIdx.x & 63;
    int quad = lane >> 4;
    int l16 = lane & 15;
    int base = blockIdx.x * 64;

    // B fragments: B[k][n], n = lane&15 (col within tile), k = quad*8 + i
    frag_ab bfrag[KS];
    int ncol = w * 16 + l16;
#pragma unroll
    for (int s = 0; s < KS; ++s) {
        frag_ab f;
#pragma unroll
        for (int i = 0; i < 8; ++i) {
            int k = s * 32 + quad * 8 + i;
            float wv = (k < KIN) ? wl[k * 64 + ncol] : wr[(k - KIN) * 64 + ncol];
            f[i] = (short)f2bf(wv);
        }
        bfrag[s] = f;
    }
    float bias = bl[ncol];

    // ---- gather phase ----
    constexpr int LPE = KIN / 2;   // lanes per edge (bf16 pairs)
    constexpr int EPW = 64 / LPE;  // edges per wave-instr
    int grp = lane / LPE;
    int p = lane % LPE;
    for (int i = 0; i < 16; ++i) {
        int node = base + w * 16 + i;
        if (node >= n) break;
        int beg = rofs[node], end = rofs[node + 1];
        float lo0 = 0.f, hi0 = 0.f, lo1 = 0.f, hi1 = 0.f;
        int e = beg;
        for (; e + 2 * EPW <= end; e += 2 * EPW) {
            int s0 = csr[e + grp];
            int s1 = csr[e + EPW + grp];
            unsigned u0 = *(const unsigned*)&hin[(size_t)s0 * KIN + 2 * p];
            unsigned u1 = *(const unsigned*)&hin[(size_t)s1 * KIN + 2 * p];
            lo0 += bf2f((unsigned short)u0); hi0 += bf2f((unsigned short)(u0 >> 16));
            lo1 += bf2f((unsigned short)u1); hi1 += bf2f((unsigned short)(u1 >> 16));
        }
        for (; e + EPW <= end; e += EPW) {
            int s0 = csr[e + grp];
            unsigned u0 = *(const unsigned*)&hin[(size_t)s0 * KIN + 2 * p];
            lo0 += bf2f((unsigned short)u0); hi0 += bf2f((unsigned short)(u0 >> 16));
        }
        if (e < end) {
            int r = end - e;
            int ok = (grp < r);
            int s0 = csr[e + (ok ? grp : 0)];
            unsigned u0 = *(const unsigned*)&hin[(size_t)s0 * KIN + 2 * p];
            if (ok) { lo0 += bf2f((unsigned short)u0); hi0 += bf2f((unsigned short)(u0 >> 16)); }
        }
        float lo = lo0 + lo1, hi = hi0 + hi1;
        if constexpr (EPW >= 4) { lo += __shfl_xor(lo, 16); hi += __shfl_xor(hi, 16); }
        lo += __shfl_xor(lo, 32); hi += __shfl_xor(hi, 32);
        int d = end - beg;
        float inv = (d > 0) ? 1.0f / (float)d : 0.0f;
        if (lane < LPE) {
            unsigned pk = (unsigned)f2bf(lo * inv) | ((unsigned)f2bf(hi * inv) << 16);
            *(unsigned*)&Ab[(w * 16 + i) * ST + 2 * p] = pk;
            unsigned su = *(const unsigned*)&hin[(size_t)node * KIN + 2 * p];
            *(unsigned*)&Ab[(w * 16 + i) * ST + KIN + 2 * p] = su;
        }
    }
    __syncthreads();

    // ---- MFMA phase: wave w computes cols [w*16, w*16+16) for 4 M-tiles ----
    frag_cd acc[4];
#pragma unroll
    for (int t = 0; t < 4; ++t) acc[t] = (frag_cd){0.f, 0.f, 0.f, 0.f};
#pragma unroll
    for (int t = 0; t < 4; ++t) {
#pragma unroll
        for (int s = 0; s < KS; ++s) {
            frag_ab af = *(frag_ab*)&Ab[(t * 16 + l16) * ST + s * 32 + quad * 8];
            acc[t] = __builtin_amdgcn_mfma_f32_16x16x32_bf16(af, bfrag[s], acc[t], 0, 0, 0);
        }
    }

    // ---- epilogue: bias, sumsq partials per node ----
    float vv[4][4];
#pragma unroll
    for (int t = 0; t < 4; ++t) {
        float q[4];
#pragma unroll
        for (int i = 0; i < 4; ++i) {
            float v = acc[t][i] + bias;   // D row = quad*4+i (node), col = l16
            vv[t][i] = v;
            q[i] = v * v;
        }
#pragma unroll
        for (int o = 1; o < 16; o <<= 1) {
#pragma unroll
            for (int i = 0; i < 4; ++i) q[i] += __shfl_xor(q[i], o);
        }
        if (l16 == 0) {
            float4 qq = make_float4(q[0], q[1], q[2], q[3]);
            *(float4*)&Nb[w * 64 + t * 16 + quad * 4] = qq;
        }
    }
    __syncthreads();

#pragma unroll
    for (int t = 0; t < 4; ++t) {
        float s0 = 0.f, s1 = 0.f, s2 = 0.f, s3 = 0.f;
#pragma unroll
        for (int ww = 0; ww < 4; ++ww) {
            float4 xq = *(const float4*)&Nb[ww * 64 + t * 16 + quad * 4];
            s0 += xq.x; s1 += xq.y; s2 += xq.z; s3 += xq.w;
        }
        float ss[4] = {s0, s1, s2, s3};
#pragma unroll
        for (int i = 0; i < 4; ++i) {
            int node = base + t * 16 + quad * 4 + i;
            if (node < n) {
                float nv = fmaxf(sqrtf(ss[i]), EPSN);
                float outv = fmaxf(vv[t][i] / nv, 0.f);
                if (OUTBF16)
                    ((unsigned short*)hout)[(size_t)node * 64 + ncol] = f2bf(outv);
                else
                    ((float*)hout)[(size_t)node * 64 + ncol] = outv;
            }
        }
    }
}

// ---------------- fused pool (batch sorted) + head MLP ------------------------
__global__ __launch_bounds__(256) void pool_mlp_k(
    const float* __restrict__ h, const int* __restrict__ batch, int n,
    const float* __restrict__ p1w, const float* __restrict__ p1b,
    const float* __restrict__ p2w, const float* __restrict__ p2b,
    const float* __restrict__ ow, const float* __restrict__ ob,
    float* __restrict__ out) {
    __shared__ float part[4][64];
    __shared__ float gmean[64];
    __shared__ float a1[64];
    __shared__ float a2[16];
    int g = blockIdx.x;
    int w = threadIdx.x >> 6, j = threadIdx.x & 63;
    int lo = 0, hi = n;
    while (lo < hi) { int m = (lo + hi) >> 1; if (batch[m] < g) lo = m + 1; else hi = m; }
    int start = lo;
    hi = n;
    while (lo < hi) { int m = (lo + hi) >> 1; if (batch[m] < g + 1) lo = m + 1; else hi = m; }
    int end = lo;
    float acc = 0.f;
    for (int node = start + w; node < end; node += 4)
        acc += h[(size_t)node * 64 + j];
    part[w][j] = acc;
    __syncthreads();
    if (w == 0) {
        float s = part[0][j] + part[1][j] + part[2][j] + part[3][j];
        float c = (float)(end - start);
        gmean[j] = s / fmaxf(c, 1.0f);
    }
    __syncthreads();
    if (w == 0) {
        float v = p1b[j];
#pragma unroll 8
        for (int k = 0; k < 64; ++k) v = fmaf(gmean[k], p1w[k * 64 + j], v);
        a1[j] = fmaxf(v, 0.f);
    }
    __syncthreads();
    if (w == 0 && j < 16) {
        float v2 = p2b[j];
#pragma unroll 8
        for (int k = 0; k < 64; ++k) v2 = fmaf(a1[k], p2w[k * 16 + j], v2);
        a2[j] = fmaxf(v2, 0.f);
    }
    __syncthreads();
    if (threadIdx.x == 0) {
        float v3 = ob[0];
#pragma unroll
        for (int k = 0; k < 16; ++k) v3 = fmaf(a2[k], ow[k], v3);
        out[g] = v3;
    }
}

extern "C" void kernel_launch(void* const* d_in, const int* in_sizes, int n_in,
                              void* d_out, int out_size, void* d_ws, size_t ws_size,
                              hipStream_t stream) {
    const float* x     = (const float*)d_in[0];
    const int*   ei    = (const int*)d_in[1];
    const int*   batch = (const int*)d_in[2];
    const float* pre_w = (const float*)d_in[4];
    const float* pre_b = (const float*)d_in[5];
    const float* c1_wl = (const float*)d_in[6];
    const float* c1_bl = (const float*)d_in[7];
    const float* c1_wr = (const float*)d_in[8];
    const float* c2_wl = (const float*)d_in[9];
    const float* c2_bl = (const float*)d_in[10];
    const float* c2_wr = (const float*)d_in[11];
    const float* p1w   = (const float*)d_in[12];
    const float* p1b   = (const float*)d_in[13];
    const float* p2w   = (const float*)d_in[14];
    const float* p2b   = (const float*)d_in[15];
    const float* ow    = (const float*)d_in[16];
    const float* ob    = (const float*)d_in[17];

    const int N = in_sizes[0] / 5;
    const int E = in_sizes[1] / 2;
    const int G = out_size;
    const int NB = (N + 255) / 256;
    const int* src = ei;
    const int* dst = ei + E;

    // workspace layout
    float* h2f = (float*)d_ws;                                // N*64 f32
    unsigned short* h0u = (unsigned short*)(h2f + (size_t)N * 64);  // N*32 bf16
    unsigned short* h1u = h0u + (size_t)N * 32;               // N*64 bf16
    int* deg      = (int*)(h1u + (size_t)N * 64);             // N
    int* rofs     = deg + N;                                  // N+1
    int* wptr     = rofs + N + 1;                             // N
    int* partials = wptr + N;                                 // NB
    int* csr      = partials + NB;                            // E

    hipMemsetAsync(deg, 0, (size_t)N * sizeof(int), stream);

    pre_linear<<<(N * 32 + 255) / 256, 256, 0, stream>>>(x, pre_w, pre_b, h0u, N);

    // CSR build (shared by both convs)
    hist_k<<<(E + 255) / 256, 256, 0, stream>>>(dst, deg, E);
    scan_block_k<<<NB, 256, 0, stream>>>(deg, rofs, partials, N);
    scan_partials_k<<<1, 64, 0, stream>>>(partials, NB);
    add_offs_k<<<(N + 256) / 256, 256, 0, stream>>>(rofs, wptr, partials, N, E);
    fill_k<<<(E + 255) / 256, 256, 0, stream>>>(src, dst, wptr, csr, E);

    conv_mfma<32, true><<<(N + 63) / 64, 256, 0, stream>>>(rofs, csr, h0u, c1_wl,
                                                           c1_bl, c1_wr, h1u, N);
    conv_mfma<64, false><<<(N + 63) / 64, 256, 0, stream>>>(rofs, csr, h1u, c2_wl,
                                                            c2_bl, c2_wr, h2f, N);

    pool_mlp_k<<<G, 256, 0, stream>>>(h2f, batch, N, p1w, p1b, p2w, p2b, ow, ob,
                                      (float*)d_out);
}

// Round 5
// 480.582 us; speedup vs baseline: 2.4044x; 1.0686x over previous
//
#include <hip/hip_runtime.h>

#define EPSN 1e-12f

using frag_ab = __attribute__((ext_vector_type(8))) short;   // 8 bf16
using frag_cd = __attribute__((ext_vector_type(4))) float;   // 4 fp32

__device__ inline unsigned short f2bf(float x) {
    union { float f; unsigned u; } v; v.f = x;
    unsigned r = v.u + 0x7fffu + ((v.u >> 16) & 1u);   // round-to-nearest-even
    return (unsigned short)(r >> 16);
}
__device__ inline float bf2f(unsigned short b) {
    union { unsigned u; float f; } v; v.u = ((unsigned)b) << 16; return v.f;
}

// ---------------- pre: h0 = relu(x @ pre_w + pre_b) -> bf16 [N,32] ------------
__global__ void pre_linear(const float* __restrict__ x, const float* __restrict__ w,
                           const float* __restrict__ b, unsigned short* __restrict__ h0,
                           int n) {
    int idx = blockIdx.x * blockDim.x + threadIdx.x;
    if (idx >= n * 32) return;
    int node = idx >> 5, j = idx & 31;
    float v = b[j];
#pragma unroll
    for (int k = 0; k < 5; ++k) v += x[node * 5 + k] * w[k * 32 + j];
    h0[idx] = f2bf(fmaxf(v, 0.f));
}

// ---------------- CSR build: histogram -> scan -> fill ------------------------
__global__ void hist_k(const int* __restrict__ dst, int* __restrict__ deg, int e) {
    int i = blockIdx.x * blockDim.x + threadIdx.x;
    if (i < e) atomicAdd(&deg[dst[i]], 1);
}

__global__ void scan_block_k(const int* __restrict__ deg, int* __restrict__ rofs,
                             int* __restrict__ partials, int n) {
    __shared__ int wsum[8];
    int i = blockIdx.x * 256 + threadIdx.x;
    int x = (i < n) ? deg[i] : 0;
    int lane = threadIdx.x & 63, w = threadIdx.x >> 6;
    int inc = x;
#pragma unroll
    for (int o = 1; o < 64; o <<= 1) {
        int t = __shfl_up(inc, o);
        if (lane >= o) inc += t;
    }
    if (lane == 63) wsum[w] = inc;
    __syncthreads();
    if (threadIdx.x == 0) {
        int s = 0;
#pragma unroll
        for (int k = 0; k < 4; ++k) { int t = wsum[k]; wsum[k] = s; s += t; }
        wsum[4] = s;
    }
    __syncthreads();
    if (i < n) rofs[i] = inc - x + wsum[w];
    if (threadIdx.x == 255) partials[blockIdx.x] = wsum[4];
}

__global__ void scan_partials_k(int* __restrict__ partials, int nb) {
    int lane = threadIdx.x;  // 64 threads
    int run = 0;
    for (int base = 0; base < nb; base += 64) {
        int i = base + lane;
        int x = (i < nb) ? partials[i] : 0;
        int inc = x;
#pragma unroll
        for (int o = 1; o < 64; o <<= 1) {
            int t = __shfl_up(inc, o);
            if (lane >= o) inc += t;
        }
        if (i < nb) partials[i] = inc - x + run;
        run += __shfl(inc, 63);
    }
}

__global__ void add_offs_k(int* __restrict__ rofs, int* __restrict__ wptr,
                           const int* __restrict__ partials, int n, int e) {
    int i = blockIdx.x * 256 + threadIdx.x;
    if (i < n) {
        int v = rofs[i] + partials[i >> 8];
        rofs[i] = v;
        wptr[i] = v;
    }
    if (i == n) rofs[n] = e;
}

__global__ void fill_k(const int* __restrict__ src, const int* __restrict__ dst,
                       int* __restrict__ wptr, int* __restrict__ csr, int e) {
    int i = blockIdx.x * blockDim.x + threadIdx.x;
    if (i < e) {
        int p = atomicAdd(&wptr[dst[i]], 1);
        csr[p] = src[i];
    }
}

// ---------------- SAGE conv via MFMA ------------------------------------------
// Block = 256 thr (4 waves) = 64 nodes. Gather: each edge row is read with
// 16B/lane uint4 loads (LPE = KIN/8 lanes per edge, EPW = 64/LPE edges per
// wave-load) so a deg-16 node needs 1-2 load rounds (was 4-8 with u32 loads:
// round-4 was gather-latency bound at VALUBusy 24%). Cross-edge reduce via
// shfl_xor; [agg|self] bf16 rows land in LDS; wave w then runs
// mfma_f32_16x16x32_bf16 for j-tile w over 4 M-tiles with weights held in
// VGPR B-fragments. Epilogue: bias, cross-wave L2 norm, relu, store.
template <int KIN, bool OUTBF16>
__global__ __launch_bounds__(256) void conv_mfma(
    const int* __restrict__ rofs, const int* __restrict__ csr,
    const unsigned short* __restrict__ hin, const float* __restrict__ wl,
    const float* __restrict__ bl, const float* __restrict__ wr,
    void* __restrict__ hout, int n) {
    constexpr int KT = 2 * KIN;    // concat [agg|self]
    constexpr int ST = KT + 8;     // LDS row stride in ushorts (16B-aligned rows)
    constexpr int KS = KT / 32;    // MFMA k-steps
    constexpr int LPE = KIN / 8;   // lanes per edge row (16B each)
    constexpr int EPW = 64 / LPE;  // edges per wave-load
    __shared__ unsigned short __attribute__((aligned(16))) Ab[64 * ST];
    __shared__ float __attribute__((aligned(16))) Nb[4 * 64];

    int w = threadIdx.x >> 6;      // wave id == j-tile
    int lane = threadIdx.x & 63;
    int quad = lane >> 4;
    int l16 = lane & 15;
    int base = blockIdx.x * 64;

    // B fragments: B[k][n], n = lane&15 (col within tile), k = quad*8 + i
    frag_ab bfrag[KS];
    int ncol = w * 16 + l16;
#pragma unroll
    for (int s = 0; s < KS; ++s) {
        frag_ab f;
#pragma unroll
        for (int i = 0; i < 8; ++i) {
            int k = s * 32 + quad * 8 + i;
            float wv = (k < KIN) ? wl[k * 64 + ncol] : wr[(k - KIN) * 64 + ncol];
            f[i] = (short)f2bf(wv);
        }
        bfrag[s] = f;
    }
    float bias = bl[ncol];

    // ---- gather phase: wave w fills LDS rows w*16 .. w*16+15 ----
    int grp = lane / LPE;          // edge slot within a wave-load
    int p = lane % LPE;            // 16B chunk within a row
    for (int i = 0; i < 16; ++i) {
        int node = base + w * 16 + i;
        if (node >= n) break;
        int beg = rofs[node], end = rofs[node + 1];
        uint4 selfv = make_uint4(0u, 0u, 0u, 0u);
        if (grp == 1)
            selfv = *(const uint4*)&hin[(size_t)node * KIN + p * 8];
        float a0 = 0.f, a1 = 0.f, a2 = 0.f, a3 = 0.f;
        float a4 = 0.f, a5 = 0.f, a6 = 0.f, a7 = 0.f;
#pragma unroll 2
        for (int e = beg; e < end; e += EPW) {
            int ee = e + grp;
            bool ok = (ee < end);
            int s = csr[ok ? ee : beg];
            uint4 u = *(const uint4*)&hin[(size_t)s * KIN + p * 8];
            if (ok) {
                a0 += bf2f((unsigned short)u.x); a1 += bf2f((unsigned short)(u.x >> 16));
                a2 += bf2f((unsigned short)u.y); a3 += bf2f((unsigned short)(u.y >> 16));
                a4 += bf2f((unsigned short)u.z); a5 += bf2f((unsigned short)(u.z >> 16));
                a6 += bf2f((unsigned short)u.w); a7 += bf2f((unsigned short)(u.w >> 16));
            }
        }
        float acc[8] = {a0, a1, a2, a3, a4, a5, a6, a7};
#pragma unroll
        for (int o = LPE; o < 64; o <<= 1) {
#pragma unroll
            for (int q = 0; q < 8; ++q) acc[q] += __shfl_xor(acc[q], o);
        }
        int d = end - beg;
        float inv = (d > 0) ? 1.0f / (float)d : 0.0f;
        if (grp == 0) {
            uint4 o4;
            o4.x = (unsigned)f2bf(acc[0] * inv) | ((unsigned)f2bf(acc[1] * inv) << 16);
            o4.y = (unsigned)f2bf(acc[2] * inv) | ((unsigned)f2bf(acc[3] * inv) << 16);
            o4.z = (unsigned)f2bf(acc[4] * inv) | ((unsigned)f2bf(acc[5] * inv) << 16);
            o4.w = (unsigned)f2bf(acc[6] * inv) | ((unsigned)f2bf(acc[7] * inv) << 16);
            *(uint4*)&Ab[(w * 16 + i) * ST + p * 8] = o4;
        } else if (grp == 1) {
            *(uint4*)&Ab[(w * 16 + i) * ST + KIN + p * 8] = selfv;
        }
    }
    __syncthreads();

    // ---- MFMA phase: wave w computes cols [w*16, w*16+16) for 4 M-tiles ----
    frag_cd acc[4];
#pragma unroll
    for (int t = 0; t < 4; ++t) acc[t] = (frag_cd){0.f, 0.f, 0.f, 0.f};
#pragma unroll
    for (int t = 0; t < 4; ++t) {
#pragma unroll
        for (int s = 0; s < KS; ++s) {
            frag_ab af = *(frag_ab*)&Ab[(t * 16 + l16) * ST + s * 32 + quad * 8];
            acc[t] = __builtin_amdgcn_mfma_f32_16x16x32_bf16(af, bfrag[s], acc[t], 0, 0, 0);
        }
    }

    // ---- epilogue: bias, sumsq partials per node ----
    float vv[4][4];
#pragma unroll
    for (int t = 0; t < 4; ++t) {
        float q[4];
#pragma unroll
        for (int i = 0; i < 4; ++i) {
            float v = acc[t][i] + bias;   // D row = quad*4+i (node), col = l16
            vv[t][i] = v;
            q[i] = v * v;
        }
#pragma unroll
        for (int o = 1; o < 16; o <<= 1) {
#pragma unroll
            for (int i = 0; i < 4; ++i) q[i] += __shfl_xor(q[i], o);
        }
        if (l16 == 0) {
            float4 qq = make_float4(q[0], q[1], q[2], q[3]);
            *(float4*)&Nb[w * 64 + t * 16 + quad * 4] = qq;
        }
    }
    __syncthreads();

#pragma unroll
    for (int t = 0; t < 4; ++t) {
        float s0 = 0.f, s1 = 0.f, s2 = 0.f, s3 = 0.f;
#pragma unroll
        for (int ww = 0; ww < 4; ++ww) {
            float4 xq = *(const float4*)&Nb[ww * 64 + t * 16 + quad * 4];
            s0 += xq.x; s1 += xq.y; s2 += xq.z; s3 += xq.w;
        }
        float ss[4] = {s0, s1, s2, s3};
#pragma unroll
        for (int i = 0; i < 4; ++i) {
            int node = base + t * 16 + quad * 4 + i;
            if (node < n) {
                float nv = fmaxf(sqrtf(ss[i]), EPSN);
                float outv = fmaxf(vv[t][i] / nv, 0.f);
                if (OUTBF16)
                    ((unsigned short*)hout)[(size_t)node * 64 + ncol] = f2bf(outv);
                else
                    ((float*)hout)[(size_t)node * 64 + ncol] = outv;
            }
        }
    }
}

// ---------------- fused pool (batch sorted) + head MLP ------------------------
__global__ __launch_bounds__(256) void pool_mlp_k(
    const float* __restrict__ h, const int* __restrict__ batch, int n,
    const float* __restrict__ p1w, const float* __restrict__ p1b,
    const float* __restrict__ p2w, const float* __restrict__ p2b,
    const float* __restrict__ ow, const float* __restrict__ ob,
    float* __restrict__ out) {
    __shared__ float part[4][64];
    __shared__ float gmean[64];
    __shared__ float a1[64];
    __shared__ float a2[16];
    int g = blockIdx.x;
    int w = threadIdx.x >> 6, j = threadIdx.x & 63;
    int lo = 0, hi = n;
    while (lo < hi) { int m = (lo + hi) >> 1; if (batch[m] < g) lo = m + 1; else hi = m; }
    int start = lo;
    hi = n;
    while (lo < hi) { int m = (lo + hi) >> 1; if (batch[m] < g + 1) lo = m + 1; else hi = m; }
    int end = lo;
    float acc = 0.f;
    for (int node = start + w; node < end; node += 4)
        acc += h[(size_t)node * 64 + j];
    part[w][j] = acc;
    __syncthreads();
    if (w == 0) {
        float s = part[0][j] + part[1][j] + part[2][j] + part[3][j];
        float c = (float)(end - start);
        gmean[j] = s / fmaxf(c, 1.0f);
    }
    __syncthreads();
    if (w == 0) {
        float v = p1b[j];
#pragma unroll 8
        for (int k = 0; k < 64; ++k) v = fmaf(gmean[k], p1w[k * 64 + j], v);
        a1[j] = fmaxf(v, 0.f);
    }
    __syncthreads();
    if (w == 0 && j < 16) {
        float v2 = p2b[j];
#pragma unroll 8
        for (int k = 0; k < 64; ++k) v2 = fmaf(a1[k], p2w[k * 16 + j], v2);
        a2[j] = fmaxf(v2, 0.f);
    }
    __syncthreads();
    if (threadIdx.x == 0) {
        float v3 = ob[0];
#pragma unroll
        for (int k = 0; k < 16; ++k) v3 = fmaf(a2[k], ow[k], v3);
        out[g] = v3;
    }
}

extern "C" void kernel_launch(void* const* d_in, const int* in_sizes, int n_in,
                              void* d_out, int out_size, void* d_ws, size_t ws_size,
                              hipStream_t stream) {
    const float* x     = (const float*)d_in[0];
    const int*   ei    = (const int*)d_in[1];
    const int*   batch = (const int*)d_in[2];
    const float* pre_w = (const float*)d_in[4];
    const float* pre_b = (const float*)d_in[5];
    const float* c1_wl = (const float*)d_in[6];
    const float* c1_bl = (const float*)d_in[7];
    const float* c1_wr = (const float*)d_in[8];
    const float* c2_wl = (const float*)d_in[9];
    const float* c2_bl = (const float*)d_in[10];
    const float* c2_wr = (const float*)d_in[11];
    const float* p1w   = (const float*)d_in[12];
    const float* p1b   = (const float*)d_in[13];
    const float* p2w   = (const float*)d_in[14];
    const float* p2b   = (const float*)d_in[15];
    const float* ow    = (const float*)d_in[16];
    const float* ob    = (const float*)d_in[17];

    const int N = in_sizes[0] / 5;
    const int E = in_sizes[1] / 2;
    const int G = out_size;
    const int NB = (N + 255) / 256;
    const int* src = ei;
    const int* dst = ei + E;

    // workspace layout
    float* h2f = (float*)d_ws;                                // N*64 f32
    unsigned short* h0u = (unsigned short*)(h2f + (size_t)N * 64);  // N*32 bf16
    unsigned short* h1u = h0u + (size_t)N * 32;               // N*64 bf16
    int* deg      = (int*)(h1u + (size_t)N * 64);             // N
    int* rofs     = deg + N;                                  // N+1
    int* wptr     = rofs + N + 1;                             // N
    int* partials = wptr + N;                                 // NB
    int* csr      = partials + NB;                            // E

    hipMemsetAsync(deg, 0, (size_t)N * sizeof(int), stream);

    pre_linear<<<(N * 32 + 255) / 256, 256, 0, stream>>>(x, pre_w, pre_b, h0u, N);

    // CSR build (shared by both convs)
    hist_k<<<(E + 255) / 256, 256, 0, stream>>>(dst, deg, E);
    scan_block_k<<<NB, 256, 0, stream>>>(deg, rofs, partials, N);
    scan_partials_k<<<1, 64, 0, stream>>>(partials, NB);
    add_offs_k<<<(N + 256) / 256, 256, 0, stream>>>(rofs, wptr, partials, N, E);
    fill_k<<<(E + 255) / 256, 256, 0, stream>>>(src, dst, wptr, csr, E);

    conv_mfma<32, true><<<(N + 63) / 64, 256, 0, stream>>>(rofs, csr, h0u, c1_wl,
                                                           c1_bl, c1_wr, h1u, N);
    conv_mfma<64, false><<<(N + 63) / 64, 256, 0, stream>>>(rofs, csr, h1u, c2_wl,
                                                            c2_bl, c2_wr, h2f, N);

    pool_mlp_k<<<G, 256, 0, stream>>>(h2f, batch, N, p1w, p1b, p2w, p2b, ow, ob,
                                      (float*)d_out);
}